// Round 1
// baseline (92.266 us; speedup 1.0000x reference)
//
#include <hip/hip_runtime.h>

#define B_   32
#define ICN  1152
#define OCN  10
#define IDN  8
#define ODN  16
#define ODH  8                  // od half width (split across 2 lanes)
#define NIT  5
#define EPS  1e-20f
#define OUTN (B_ * OCN * ODN)   // 5120
#define BGRP 11                 // ceil(32 b / 3 groups per wave)
#define NBLK (BGRP * ICN)       // 12672 one-wave blocks

// Pair-swap lanes (2k,2k+1) via DPP quad_perm [1,0,3,2] = 0xB1.
// Pure VALU (~2 cyc), replaces ds_bpermute-based __shfl_xor(x,1) which put a
// ~100-cycle LDS-pipe round trip + lgkmcnt wait on the NNMF dependency chain.
__device__ __forceinline__ float dpp_swap1(float x) {
  return __int_as_float(__builtin_amdgcn_update_dpp(
      0, __float_as_int(x), 0xB1, 0xF, 0xF, true));
}

// ---------------------------------------------------------------------------
// One wave (64 lanes) = 3 (b,ic) groups of 20 lanes (10 oc x 2 od-halves),
// lanes 60..63 idle. Each lane keeps its 8x8 weight slice in REGISTERS
// (64 VGPRs), runs 5 NNMF iterations. All od-pair reductions are DPP
// quad-perm swaps (VALU-only); the only DS ops left are the 10 alpha
// bpermutes, once per wave. NNMF loop is phase-batched so the 8 id-chains
// interleave (ILP) instead of serializing.
// No LDS, no barriers. Partial [5120] per ic goes to ws; reduce kernel sums.
// ---------------------------------------------------------------------------
__global__ __launch_bounds__(64, 4) void caps_main(
    const float* __restrict__ xg, const float* __restrict__ wg,
    float* __restrict__ ws, float* __restrict__ outg, int atomic_out) {
  const int l = threadIdx.x;
  const int bid = blockIdx.x;
  const int ic = bid % ICN;      // same-ic blocks 1152 apart -> same XCD (1152%8==0)
  const int bgrp = bid / ICN;    // 0..10
  const int grp = l / 20;        // 0..3 (3 = idle lanes 60..63)
  const int q = l % 20;
  const int oc = q >> 1;         // 0..9
  const int half = q & 1;        // 0,1
  const int b = bgrp * 3 + grp;
  const bool valid = (grp < 3) && (b < B_);
  const int bb = (b < B_) ? b : (B_ - 1);   // clamp for loads only

  // ---- weights slice -> registers: w[ic][oc][id][half*8 .. +8) ----
  float wr[IDN][ODH];
  {
    const float* wp = wg + ((size_t)ic * OCN + oc) * (IDN * ODN) + half * ODH;
#pragma unroll
    for (int id = 0; id < IDN; ++id) {
      const float4 v0 = *(const float4*)(wp + id * ODN);
      const float4 v1 = *(const float4*)(wp + id * ODN + 4);
      wr[id][0] = v0.x; wr[id][1] = v0.y; wr[id][2] = v0.z; wr[id][3] = v0.w;
      wr[id][4] = v1.x; wr[id][5] = v1.y; wr[id][6] = v1.z; wr[id][7] = v1.w;
    }
  }

  // ---- x[b,ic,:] normalized over id ----
  float xn[IDN];
  {
    const float* xp = xg + ((size_t)bb * ICN + ic) * IDN;
    const float4 a0 = ((const float4*)xp)[0];
    const float4 a1 = ((const float4*)xp)[1];
    xn[0] = a0.x; xn[1] = a0.y; xn[2] = a0.z; xn[3] = a0.w;
    xn[4] = a1.x; xn[5] = a1.y; xn[6] = a1.z; xn[7] = a1.w;
    const float s = ((xn[0] + xn[1]) + (xn[2] + xn[3])) +
                    ((xn[4] + xn[5]) + (xn[6] + xn[7]));
    const float r = __builtin_amdgcn_rcpf(s + EPS);
#pragma unroll
    for (int i = 0; i < IDN; ++i) xn[i] *= r;
  }

  // ---- NNMF iterations (phase-batched for ILP, DPP for pair reductions) ----
  float h[ODH];
#pragma unroll
  for (int k = 0; k < ODH; ++k) h[k] = 1.0f / ODN;

  for (int it = 0; it < NIT; ++it) {
    // phase 1: 8 independent dot products pd[id] = sum_k h[k]*w[id][k]
    float pd[IDN];
#pragma unroll
    for (int id = 0; id < IDN; ++id) {
      float p = 0.f;
#pragma unroll
      for (int k = 0; k < ODH; ++k) p = fmaf(h[k], wr[id][k], p);
      pd[id] = p;
    }
    // phase 2: 8 independent pair-swaps + rcps -> tc[id]
    float tc[IDN];
#pragma unroll
    for (int id = 0; id < IDN; ++id) {
      const float den = pd[id] + dpp_swap1(pd[id]);   // full 16-od sum
      tc[id] = xn[id] * __builtin_amdgcn_rcpf(den + EPS);
    }
    // phase 3: hacc[k] = sum_id w[id][k]*tc[id]  (8 indep chains over k)
    float hacc[ODH];
#pragma unroll
    for (int k = 0; k < ODH; ++k) hacc[k] = wr[0][k] * tc[0];
#pragma unroll
    for (int id = 1; id < IDN; ++id)
#pragma unroll
      for (int k = 0; k < ODH; ++k) hacc[k] = fmaf(wr[id][k], tc[id], hacc[k]);
    // h update + normalize over od (tree sum + DPP pair swap)
#pragma unroll
    for (int k = 0; k < ODH; ++k) h[k] *= hacc[k];
    const float ps = ((h[0] + h[1]) + (h[2] + h[3])) +
                     ((h[4] + h[5]) + (h[6] + h[7]));
    const float hs = ps + dpp_swap1(ps);              // full 16-od sum
    const float r = __builtin_amdgcn_rcpf(hs + EPS);
#pragma unroll
    for (int k = 0; k < ODH; ++k) h[k] *= r;
  }

  // ---- alpha = sum_id (sum_od h*w) * xn, normalized over oc ----
  float ap = 0.f;
#pragma unroll
  for (int id = 0; id < IDN; ++id) {
    float rec = 0.f;
#pragma unroll
    for (int k = 0; k < ODH; ++k) rec = fmaf(h[k], wr[id][k], rec);
    ap = fmaf(rec, xn[id], ap);
  }
  const float af = ap + dpp_swap1(ap);                // full alpha(b,ic,oc)
  float asum = 0.f;
  const int gbase = grp * 20;
#pragma unroll
  for (int k = 0; k < OCN; ++k) asum += __shfl(af, gbase + 2 * k, 64);
  const float an = af * __builtin_amdgcn_rcpf(asum + EPS);

  float o[ODH];
#pragma unroll
  for (int k = 0; k < ODH; ++k) o[k] = h[k] * an;

  if (valid) {
    if (!atomic_out) {
      float* dst = ws + (size_t)ic * OUTN + (bb * OCN + oc) * ODN + half * ODH;
      float4 v0, v1;
      v0.x = o[0]; v0.y = o[1]; v0.z = o[2]; v0.w = o[3];
      v1.x = o[4]; v1.y = o[5]; v1.z = o[6]; v1.w = o[7];
      ((float4*)dst)[0] = v0;
      ((float4*)dst)[1] = v1;
    } else {
      const int base = (bb * OCN + oc) * ODN + half * ODH;
#pragma unroll
      for (int k = 0; k < ODH; ++k) atomicAdd(outg + base + k, o[k]);
    }
  }
}

// ---------------------------------------------------------------------------
// Reduce: out[j] += sum_{r in my 36 rows} ws[r][j].
// grid = (5120/256, 32), block 256 -> 640 blocks / 2560 waves, 36 independent
// loads each (MLP), 32 atomic contenders per address (out pre-zeroed).
// ---------------------------------------------------------------------------
#define RSPLIT 32
#define RROWS  (ICN / RSPLIT)   // 36
__global__ void caps_reduce(const float* __restrict__ ws, float* __restrict__ outg) {
  const int j = blockIdx.x * 256 + threadIdx.x;
  const int r0 = blockIdx.y * RROWS;
  float s = 0.f;
#pragma unroll
  for (int r = 0; r < RROWS; ++r) s += ws[(size_t)(r0 + r) * OUTN + j];
  atomicAdd(outg + j, s);
}

extern "C" void kernel_launch(void* const* d_in, const int* in_sizes, int n_in,
                              void* d_out, int out_size, void* d_ws, size_t ws_size,
                              hipStream_t stream) {
  const float* x = (const float*)d_in[0];
  const float* w = (const float*)d_in[1];
  float* out = (float*)d_out;
  float* ws = (float*)d_ws;

  hipMemsetAsync(out, 0, OUTN * sizeof(float), stream);

  const size_t need = (size_t)ICN * OUTN * sizeof(float);  // 23.6 MB

  if (ws_size >= need) {
    caps_main<<<NBLK, 64, 0, stream>>>(x, w, ws, out, 0);
    caps_reduce<<<dim3(OUTN / 256, RSPLIT), 256, 0, stream>>>(ws, out);
  } else {
    caps_main<<<NBLK, 64, 0, stream>>>(x, w, nullptr, out, 1);
  }
}